// Round 3
// baseline (1347.998 us; speedup 1.0000x reference)
//
#include <hip/hip_runtime.h>

#define CH   128
#define OC   3
#define WDIM 512
#define HW   (512 * 512)
#define HW4  (HW / 4)          // 65536 float4 groups per (b,c) plane

typedef float f4 __attribute__((ext_vector_type(4)));

// -------- Kernel 1: compute modulated+demodulated weights w[b,o,c] --------
// grid = B (8), block = CH (128). thread = channel c.
__global__ void modweights_kernel(const float* __restrict__ styles,      // [B, WDIM]
                                  const float* __restrict__ conv_weight, // [OC, CH]
                                  const float* __restrict__ aff_weight,  // [CH, WDIM]
                                  const float* __restrict__ aff_bias,    // [CH]
                                  float* __restrict__ wmod) {            // [B, OC, CH]
    const int b = blockIdx.x;
    const int c = threadIdx.x;
    const float AFF_SCALE  = 0.04419417382415922f;   // 1/sqrt(512)
    const float CONV_SCALE = 0.08838834764831845f;   // 1/sqrt(128)

    const f4* s4 = (const f4*)(styles + (size_t)b * WDIM);
    const f4* a4 = (const f4*)(aff_weight + (size_t)c * WDIM);
    float acc = 0.0f;
#pragma unroll 4
    for (int k = 0; k < WDIM / 4; ++k) {
        f4 sv = s4[k];
        f4 av = a4[k];
        acc += sv.x * av.x + sv.y * av.y + sv.z * av.z + sv.w * av.w;
    }
    const float z = acc * AFF_SCALE + aff_bias[c];

    float wv[OC];
#pragma unroll
    for (int o = 0; o < OC; ++o)
        wv[o] = conv_weight[o * CH + c] * z * CONV_SCALE;

    __shared__ float red[CH];
    float ss[OC];
#pragma unroll
    for (int o = 0; o < OC; ++o) {
        red[c] = wv[o] * wv[o];
        __syncthreads();
        for (int s = CH / 2; s > 0; s >>= 1) {
            if (c < s) red[c] += red[c + s];
            __syncthreads();
        }
        ss[o] = red[0];
        __syncthreads();
    }

#pragma unroll
    for (int o = 0; o < OC; ++o) {
        const float demod = rsqrtf(ss[o] + 1e-8f);
        wmod[((size_t)b * OC + o) * CH + c] = wv[o] * demod;
    }
}

// -------- Kernel 2: out[b,o,hw] = sum_c w[b,o,c] * x[b,c,hw] + bias[o] --------
// 512-thread blocks, ONE float4 group per thread: same 8 KB contiguous chunk
// per plane per block as before, but 8 waves/block x 4 blocks/CU = 32 waves/CU
// (2x round-2 occupancy). unroll 4 -> 4 dwordx4 in flight/thread, VGPR ~45
// so 8 waves/EU fits (<=64 VGPR). Nontemporal: pure streaming, zero reuse.
__global__ __launch_bounds__(512, 8) void torgb_kernel(const float* __restrict__ x,
                                                       const float* __restrict__ wmod,
                                                       const float* __restrict__ conv_bias,
                                                       float* __restrict__ out) {
    const int b   = blockIdx.x >> 7;                 // 128 blocks per sample
    const int blk = blockIdx.x & 127;
    const int g0  = (blk << 9) + threadIdx.x;        // [0, HW4)

    __shared__ float wsh[OC * CH];
    if (threadIdx.x < OC * CH)
        wsh[threadIdx.x] = wmod[(size_t)b * OC * CH + threadIdx.x];
    __syncthreads();

    const f4* xb = (const f4*)x + (size_t)b * CH * HW4 + g0;

    f4 a0 = (f4)0.f, a1 = (f4)0.f, a2 = (f4)0.f;

#pragma unroll 4
    for (int c = 0; c < CH; ++c) {
        const f4 u = __builtin_nontemporal_load(&xb[(size_t)c * HW4]);
        a0 += u * wsh[c];
        a1 += u * wsh[CH + c];
        a2 += u * wsh[2 * CH + c];
    }

    a0 += conv_bias[0];
    a1 += conv_bias[1];
    a2 += conv_bias[2];

    f4* o4 = (f4*)out + (size_t)b * OC * HW4 + g0;
    __builtin_nontemporal_store(a0, &o4[0 * HW4]);
    __builtin_nontemporal_store(a1, &o4[1 * HW4]);
    __builtin_nontemporal_store(a2, &o4[2 * HW4]);
}

extern "C" void kernel_launch(void* const* d_in, const int* in_sizes, int n_in,
                              void* d_out, int out_size, void* d_ws, size_t ws_size,
                              hipStream_t stream) {
    const float* x           = (const float*)d_in[0]; // [8,128,512,512]
    const float* styles      = (const float*)d_in[1]; // [8,512]
    const float* conv_weight = (const float*)d_in[2]; // [3,128]
    const float* conv_bias   = (const float*)d_in[3]; // [3]
    const float* aff_weight  = (const float*)d_in[4]; // [128,512]
    const float* aff_bias    = (const float*)d_in[5]; // [128]
    float* out  = (float*)d_out;                      // [8,3,512,512]
    float* wmod = (float*)d_ws;                       // [8,3,128] scratch (12 KB)

    const int B = 8;
    modweights_kernel<<<B, CH, 0, stream>>>(styles, conv_weight, aff_weight, aff_bias, wmod);
    torgb_kernel<<<B * 128, 512, 0, stream>>>(x, wmod, conv_bias, out);
}